// Round 4
// baseline (2113.656 us; speedup 1.0000x reference)
//
#include <hip/hip_runtime.h>
#include <hip/hip_bf16.h>
#include <math.h>

#define BB 64      // batch
#define CC 64      // width/channels
#define SS 8192    // sequence
#define NMODE 256  // kept rfft modes
#define KK2 512    // 2*NMODE (re/im interleaved)

typedef __attribute__((ext_vector_type(8))) short short8;
typedef __attribute__((ext_vector_type(4))) float f32x4;

__device__ __forceinline__ float gelu_exact(float v) {
    return 0.5f * v * (1.0f + erff(v * 0.7071067811865476f));
}

__device__ __forceinline__ float b2f(ushort u) {
    return __uint_as_float(((unsigned int)u) << 16);
}
__device__ __forceinline__ ushort f2b(float v) {
    __hip_bfloat16 h = __float2bfloat16(v);  // RNE
    return *(ushort*)&h;
}
__device__ __forceinline__ void split2(float v, ushort& h, ushort& l) {
    h = f2b(v);
    l = f2b(v - b2f(h));
}

// async global->LDS, 16 B per lane, dest = (wave-uniform base) + lane*16
__device__ __forceinline__ void async16(void* lds, const void* g) {
    __builtin_amdgcn_global_load_lds(
        (const __attribute__((address_space(1))) unsigned int*)g,
        (__attribute__((address_space(3))) unsigned int*)lds, 16, 0, 0);
}

// ---------------- DFT basis tables (bf16 hi/lo pairs) ----------------
__global__ void build_T1(ushort* __restrict__ h, ushort* __restrict__ l) {
    int c = blockIdx.x;
    int n = blockIdx.y * 256 + threadIdx.x;
    int k = c >> 1;
    int m = (n * k) & (SS - 1);
    float th = (float)m * (6.283185307179586476925f / (float)SS);
    float s, co;
    sincosf(th, &s, &co);
    float v = (c & 1) ? -s : co;
    ushort hh, ll;
    split2(v, hh, ll);
    h[(size_t)c * SS + n] = hh;
    l[(size_t)c * SS + n] = ll;
}

__global__ void build_T2(ushort* __restrict__ h, ushort* __restrict__ l) {
    int n = blockIdx.x;
    int c = blockIdx.y * 256 + threadIdx.x;
    int k = c >> 1;
    int m = (n * k) & (SS - 1);
    float th = (float)m * (6.283185307179586476925f / (float)SS);
    float s, co;
    sincosf(th, &s, &co);
    float v = (c & 1) ? -s : co;
    ushort hh, ll;
    split2(v, hh, ll);
    h[(size_t)n * KK2 + c] = hh;
    l[(size_t)n * KK2 + c] = ll;
}

__global__ void zero_xf(float* __restrict__ p) {
    size_t i = ((size_t)blockIdx.x * 256 + threadIdx.x) * 4;
    *(float4*)&p[i] = make_float4(0.f, 0.f, 0.f, 0.f);
}

// ---------------- lifting layer (writes split x) ----------------
__global__ void lift_kernel(const float* __restrict__ u, const float* __restrict__ w0,
                            const float* __restrict__ b0, ushort* __restrict__ xh,
                            ushort* __restrict__ xl) {
    int n = blockIdx.x * 256 + threadIdx.x;
    int c = blockIdx.y;
    int b = blockIdx.z;
    float uv = u[b * SS + n];
    float g = (float)n * (1.0f / (float)(SS - 1));
    float v = uv * w0[c] + g * w0[CC + c] + b0[c];
    ushort hh, ll;
    split2(v, hh, ll);
    size_t idx = (size_t)(b * CC + c) * SS + n;
    xh[idx] = hh;
    xl[idx] = ll;
}

// ---------------- forward truncated DFT: split-bf16 MFMA GEMM ----------------
// Xf[4096][512] += X[m][n] * T1[c][n]; K split 8 ways (blockIdx.z), atomic acc.
// LDS layout per operand: [4 k-groups][128 rows][8 ushort] - conflict-free and
// global_load_lds-compatible (contiguous lane*16B per wave instruction).
__global__ __launch_bounds__(256) void dft_mfma(const ushort* __restrict__ xh,
                                                const ushort* __restrict__ xl,
                                                const ushort* __restrict__ t1h,
                                                const ushort* __restrict__ t1l,
                                                float* __restrict__ Xf) {
    __shared__ __align__(16) ushort As_h[4 * 128 * 8], As_l[4 * 128 * 8];
    __shared__ __align__(16) ushort Bs_h[4 * 128 * 8], Bs_l[4 * 128 * 8];
    const int t = threadIdx.x;
    const int c0 = blockIdx.x * 128;
    const int m0 = blockIdx.y * 128;
    const int kz = blockIdx.z * (SS / 8);
    const int lane = t & 63, w = t >> 6;
    const int wm = (w >> 1) * 64, wn = (w & 1) * 64;
    const int fr = lane & 15, g = lane >> 4;
    const int rh = (w & 1) * 64;  // staging row-half
    const int hh = w >> 1;        // staging k-half (16 ushorts)

    f32x4 acc[4][4];
#pragma unroll
    for (int i = 0; i < 4; i++)
#pragma unroll
        for (int j = 0; j < 4; j++) acc[i][j] = (f32x4)0.f;

    const size_t arow = (size_t)(m0 + rh + lane) * SS;
    const size_t brow = (size_t)(c0 + rh + lane) * SS;
    const int d0 = ((2 * hh + 0) * 128 + rh) * 8;  // LDS dest (ushort idx)
    const int d1 = ((2 * hh + 1) * 128 + rh) * 8;

    for (int kt = kz; kt < kz + SS / 8; kt += 32) {
        const int kc = kt + hh * 16;
        __syncthreads();
        async16(&As_h[d0], &xh[arow + kc]);
        async16(&As_h[d1], &xh[arow + kc + 8]);
        async16(&As_l[d0], &xl[arow + kc]);
        async16(&As_l[d1], &xl[arow + kc + 8]);
        async16(&Bs_h[d0], &t1h[brow + kc]);
        async16(&Bs_h[d1], &t1h[brow + kc + 8]);
        async16(&Bs_l[d0], &t1l[brow + kc]);
        async16(&Bs_l[d1], &t1l[brow + kc + 8]);
        __syncthreads();
        short8 ah[4], al[4];
#pragma unroll
        for (int mt = 0; mt < 4; mt++) {
            int off = (g * 128 + wm + mt * 16 + fr) * 8;
            ah[mt] = *(const short8*)&As_h[off];
            al[mt] = *(const short8*)&As_l[off];
        }
#pragma unroll
        for (int nt = 0; nt < 4; nt++) {
            int off = (g * 128 + wn + nt * 16 + fr) * 8;
            short8 bh = *(const short8*)&Bs_h[off];
            short8 bl = *(const short8*)&Bs_l[off];
#pragma unroll
            for (int mt = 0; mt < 4; mt++) {
                acc[mt][nt] = __builtin_amdgcn_mfma_f32_16x16x32_bf16(ah[mt], bh, acc[mt][nt], 0, 0, 0);
                acc[mt][nt] = __builtin_amdgcn_mfma_f32_16x16x32_bf16(ah[mt], bl, acc[mt][nt], 0, 0, 0);
                acc[mt][nt] = __builtin_amdgcn_mfma_f32_16x16x32_bf16(al[mt], bh, acc[mt][nt], 0, 0, 0);
            }
        }
    }
    const int rr = g * 4;
#pragma unroll
    for (int mt = 0; mt < 4; mt++) {
        int m = m0 + wm + mt * 16 + rr;
#pragma unroll
        for (int nt = 0; nt < 4; nt++) {
            int c = c0 + wn + nt * 16 + fr;
#pragma unroll
            for (int r = 0; r < 4; r++)
                atomicAdd(&Xf[(size_t)(m + r) * KK2 + c], acc[mt][nt][r]);
        }
    }
}

// ---------------- mode mixing (fp32, 2x2 micro-tile, writes split om) --------
__global__ __launch_bounds__(256) void mode_mix(const float* __restrict__ Xf,
                                                const float* __restrict__ swr,
                                                const float* __restrict__ swi,
                                                ushort* __restrict__ omh,
                                                ushort* __restrict__ oml, int l) {
    int k = threadIdx.x;
    int bg = blockIdx.x * 2;
    int og = blockIdx.y * 2;
    float ar[2][2] = {}, ai[2][2] = {};
#pragma unroll 2
    for (int i = 0; i < CC; i++) {
        float2 x0 = *(const float2*)&Xf[((size_t)(bg + 0) * CC + i) * KK2 + 2 * k];
        float2 x1 = *(const float2*)&Xf[((size_t)(bg + 1) * CC + i) * KK2 + 2 * k];
        size_t wb = ((size_t)(l * CC + i) * CC + og) * NMODE + k;
        float wr0 = swr[wb], wi0 = swi[wb];
        float wr1 = swr[wb + NMODE], wi1 = swi[wb + NMODE];
        ar[0][0] += x0.x * wr0 - x0.y * wi0;
        ai[0][0] += x0.x * wi0 + x0.y * wr0;
        ar[0][1] += x0.x * wr1 - x0.y * wi1;
        ai[0][1] += x0.x * wi1 + x0.y * wr1;
        ar[1][0] += x1.x * wr0 - x1.y * wi0;
        ai[1][0] += x1.x * wi0 + x1.y * wr0;
        ar[1][1] += x1.x * wr1 - x1.y * wi1;
        ai[1][1] += x1.x * wi1 + x1.y * wr1;
    }
    float ck = (k == 0) ? (1.0f / (float)SS) : (2.0f / (float)SS);
#pragma unroll
    for (int b2 = 0; b2 < 2; b2++)
#pragma unroll
        for (int oo = 0; oo < 2; oo++) {
            float re = ar[b2][oo] * ck;
            float im = ai[b2][oo] * ck;
            ushort hr, lr2, hi2, li2;
            split2(re, hr, lr2);
            split2(im, hi2, li2);
            size_t base = ((size_t)(bg + b2) * CC + og + oo) * KK2 + 2 * k;
            *(ushort2*)&omh[base] = make_ushort2(hr, hi2);
            *(ushort2*)&oml[base] = make_ushort2(lr2, li2);
        }
}

// ---------------- inverse DFT + pointwise + bias + gelu (MFMA, in place) ----
// Phase 1: K=512 modes via LDS (same conflict-free layout + global_load_lds).
// Phase 2: K=64 channels, fragments gathered directly from global (no LDS).
__global__ __launch_bounds__(256) void inv_mfma(const ushort* __restrict__ omh,
                                                const ushort* __restrict__ oml,
                                                const ushort* __restrict__ t2h,
                                                const ushort* __restrict__ t2l,
                                                const float* __restrict__ pww,
                                                const float* __restrict__ pwb,
                                                ushort* __restrict__ xh,
                                                ushort* __restrict__ xl, int l,
                                                int gel) {
    __shared__ __align__(16) ushort As_h[4 * 128 * 8], As_l[4 * 128 * 8];
    __shared__ __align__(16) ushort Bs_h[4 * 128 * 8], Bs_l[4 * 128 * 8];
    const int t = threadIdx.x;
    const int n0 = blockIdx.x * 128;
    const int row0 = blockIdx.y * 128;
    const int lane = t & 63, w = t >> 6;
    const int wm = (w >> 1) * 64, wn = (w & 1) * 64;
    const int fr = lane & 15, g = lane >> 4;
    const int rh = (w & 1) * 64;
    const int hh = w >> 1;

    f32x4 acc[4][4];
#pragma unroll
    for (int i = 0; i < 4; i++)
#pragma unroll
        for (int j = 0; j < 4; j++) acc[i][j] = (f32x4)0.f;

    const size_t arow = (size_t)(row0 + rh + lane) * KK2;
    const size_t brow = (size_t)(n0 + rh + lane) * KK2;
    const int d0 = ((2 * hh + 0) * 128 + rh) * 8;
    const int d1 = ((2 * hh + 1) * 128 + rh) * 8;

    // phase 1: modes (16 steps of K=32)
    for (int kt = 0; kt < KK2; kt += 32) {
        const int kc = kt + hh * 16;
        __syncthreads();
        async16(&As_h[d0], &omh[arow + kc]);
        async16(&As_h[d1], &omh[arow + kc + 8]);
        async16(&As_l[d0], &oml[arow + kc]);
        async16(&As_l[d1], &oml[arow + kc + 8]);
        async16(&Bs_h[d0], &t2h[brow + kc]);
        async16(&Bs_h[d1], &t2h[brow + kc + 8]);
        async16(&Bs_l[d0], &t2l[brow + kc]);
        async16(&Bs_l[d1], &t2l[brow + kc + 8]);
        __syncthreads();
        short8 ah[4], al[4];
#pragma unroll
        for (int mt = 0; mt < 4; mt++) {
            int off = (g * 128 + wm + mt * 16 + fr) * 8;
            ah[mt] = *(const short8*)&As_h[off];
            al[mt] = *(const short8*)&As_l[off];
        }
#pragma unroll
        for (int nt = 0; nt < 4; nt++) {
            int off = (g * 128 + wn + nt * 16 + fr) * 8;
            short8 bh = *(const short8*)&Bs_h[off];
            short8 bl = *(const short8*)&Bs_l[off];
#pragma unroll
            for (int mt = 0; mt < 4; mt++) {
                acc[mt][nt] = __builtin_amdgcn_mfma_f32_16x16x32_bf16(ah[mt], bh, acc[mt][nt], 0, 0, 0);
                acc[mt][nt] = __builtin_amdgcn_mfma_f32_16x16x32_bf16(ah[mt], bl, acc[mt][nt], 0, 0, 0);
                acc[mt][nt] = __builtin_amdgcn_mfma_f32_16x16x32_bf16(al[mt], bh, acc[mt][nt], 0, 0, 0);
            }
        }
    }
    // phase 2: pointwise conv (2 steps of 32 channels, no LDS)
    const int xrowb = row0 + wm;  // this wave's batch base row (batch*64)
#pragma unroll
    for (int s = 0; s < 2; s++) {
        const int i0 = s * 32;
        short8 pah[4], pal[4];
#pragma unroll
        for (int mt = 0; mt < 4; mt++) {
            int o = mt * 16 + fr;
            const float* pp = &pww[(size_t)(l * CC + o) * CC + i0 + g * 8];
            float4 pa = *(const float4*)pp;
            float4 pb = *(const float4*)(pp + 4);
            float pv[8] = {pa.x, pa.y, pa.z, pa.w, pb.x, pb.y, pb.z, pb.w};
#pragma unroll
            for (int e = 0; e < 8; e++) {
                ushort h2, l2;
                split2(pv[e], h2, l2);
                pah[mt][e] = (short)h2;
                pal[mt][e] = (short)l2;
            }
        }
#pragma unroll
        for (int nt = 0; nt < 4; nt++) {
            int ncol = n0 + wn + nt * 16 + fr;
            short8 bh, bl;
#pragma unroll
            for (int j = 0; j < 8; j++) {
                size_t gxi = (size_t)(xrowb + i0 + g * 8 + j) * SS + ncol;
                bh[j] = (short)xh[gxi];
                bl[j] = (short)xl[gxi];
            }
#pragma unroll
            for (int mt = 0; mt < 4; mt++) {
                acc[mt][nt] = __builtin_amdgcn_mfma_f32_16x16x32_bf16(pah[mt], bh, acc[mt][nt], 0, 0, 0);
                acc[mt][nt] = __builtin_amdgcn_mfma_f32_16x16x32_bf16(pah[mt], bl, acc[mt][nt], 0, 0, 0);
                acc[mt][nt] = __builtin_amdgcn_mfma_f32_16x16x32_bf16(pal[mt], bh, acc[mt][nt], 0, 0, 0);
            }
        }
    }
    // epilogue: bias + gelu + split-store (in place; block owns rows x cols)
    const int rr = g * 4;
#pragma unroll
    for (int mt = 0; mt < 4; mt++) {
        int rl = wm + mt * 16 + rr;
#pragma unroll
        for (int r = 0; r < 4; r++) {
            int o = (rl + r) & 63;
            float bias = pwb[l * CC + o];
#pragma unroll
            for (int nt = 0; nt < 4; nt++) {
                int n = n0 + wn + nt * 16 + fr;
                float v = acc[mt][nt][r] + bias;
                if (gel) v = gelu_exact(v);
                ushort h2, l2;
                split2(v, h2, l2);
                size_t gg = (size_t)(row0 + rl + r) * SS + n;
                xh[gg] = h2;
                xl[gg] = l2;
            }
        }
    }
}

// ---------------- projection head ----------------
__global__ __launch_bounds__(256) void head_kernel(const ushort* __restrict__ xh,
                                                   const ushort* __restrict__ xl,
                                                   const float* __restrict__ w1,
                                                   const float* __restrict__ b1,
                                                   const float* __restrict__ w2,
                                                   const float* __restrict__ b2,
                                                   float* __restrict__ out) {
    __shared__ float Xs[64][64];
    __shared__ float W1s[64][128];
    __shared__ float part[4][64];
    int b = blockIdx.y;
    int n0 = blockIdx.x * 64;
    int tid = threadIdx.x;
    {
        int c = tid >> 2, nq = tid & 3;
        size_t gx = (size_t)(b * CC + c) * SS + n0 + nq * 16;
        short8 hA = *(const short8*)&xh[gx];
        short8 hB = *(const short8*)&xh[gx + 8];
        short8 lA = *(const short8*)&xl[gx];
        short8 lB = *(const short8*)&xl[gx + 8];
#pragma unroll
        for (int e = 0; e < 8; e++) {
            Xs[c][nq * 16 + e] = b2f((ushort)hA[e]) + b2f((ushort)lA[e]);
            Xs[c][nq * 16 + 8 + e] = b2f((ushort)hB[e]) + b2f((ushort)lB[e]);
        }
    }
    float* w1flat = &W1s[0][0];
#pragma unroll
    for (int q = 0; q < 8; q++) {
        int off = q * 1024 + tid * 4;
        *(float4*)&w1flat[off] = *(const float4*)&w1[off];
    }
    __syncthreads();
    int nn = tid & 63, jg = tid >> 6;
    float h[32];
#pragma unroll
    for (int jj = 0; jj < 32; jj++) h[jj] = b1[jg * 32 + jj];
    for (int c = 0; c < 64; c++) {
        float xv = Xs[c][nn];
#pragma unroll
        for (int jj = 0; jj < 32; jj++)
            h[jj] = fmaf(xv, W1s[c][jg * 32 + jj], h[jj]);
    }
    float p = 0.f;
#pragma unroll
    for (int jj = 0; jj < 32; jj++)
        p = fmaf(gelu_exact(h[jj]), w2[jg * 32 + jj], p);
    part[jg][nn] = p;
    __syncthreads();
    if (tid < 64) {
        float v = part[0][tid] + part[1][tid] + part[2][tid] + part[3][tid] + b2[0];
        out[b * SS + n0 + tid] = v;
    }
}

extern "C" void kernel_launch(void* const* d_in, const int* in_sizes, int n_in,
                              void* d_out, int out_size, void* d_ws, size_t ws_size,
                              hipStream_t stream) {
    (void)in_sizes; (void)n_in; (void)out_size; (void)ws_size;
    const float* u = (const float*)d_in[0];
    const float* fc0_w = (const float*)d_in[1];
    const float* fc0_b = (const float*)d_in[2];
    const float* sw_r = (const float*)d_in[3];
    const float* sw_i = (const float*)d_in[4];
    const float* pw_w = (const float*)d_in[5];
    const float* pw_b = (const float*)d_in[6];
    const float* fc1_w = (const float*)d_in[7];
    const float* fc1_b = (const float*)d_in[8];
    const float* fc2_w = (const float*)d_in[9];
    const float* fc2_b = (const float*)d_in[10];
    float* out = (float*)d_out;

    // workspace layout (total = 184,549,376 B)
    char* ws = (char*)d_ws;
    ushort* xh = (ushort*)ws;                        // 33,554,432 els
    ushort* xl = (ushort*)(ws + 67108864);           // 33,554,432
    ushort* t1h = (ushort*)(ws + 134217728);         // [512][8192]
    ushort* t1l = (ushort*)(ws + 142606336);
    ushort* t2h = (ushort*)(ws + 150994944);         // [8192][512]
    ushort* t2l = (ushort*)(ws + 159383552);
    ushort* omh = (ushort*)(ws + 167772160);         // [4096][512]
    ushort* oml = (ushort*)(ws + 171966464);
    float* Xf = (float*)(ws + 176160768);            // [4096][512] fp32

    build_T1<<<dim3(KK2, SS / 256), 256, 0, stream>>>(t1h, t1l);
    build_T2<<<dim3(SS, KK2 / 256), 256, 0, stream>>>(t2h, t2l);
    lift_kernel<<<dim3(SS / 256, CC, BB), 256, 0, stream>>>(u, fc0_w, fc0_b, xh, xl);

    for (int l = 0; l < 4; l++) {
        zero_xf<<<dim3(2048), 256, 0, stream>>>(Xf);
        dft_mfma<<<dim3(KK2 / 128, (BB * CC) / 128, 8), 256, 0, stream>>>(
            xh, xl, t1h, t1l, Xf);
        mode_mix<<<dim3(BB / 2, CC / 2), 256, 0, stream>>>(Xf, sw_r, sw_i, omh, oml, l);
        inv_mfma<<<dim3(SS / 128, BB / 2), 256, 0, stream>>>(
            omh, oml, t2h, t2l, pw_w, pw_b, xh, xl, l, (l < 3) ? 1 : 0);
    }
    head_kernel<<<dim3(SS / 64, BB), 256, 0, stream>>>(xh, xl, fc1_w, fc1_b, fc2_w,
                                                       fc2_b, out);
}

// Round 5
// 1883.850 us; speedup vs baseline: 1.1220x; 1.1220x over previous
//
#include <hip/hip_runtime.h>
#include <hip/hip_bf16.h>
#include <math.h>

#define BB 64      // batch
#define CC 64      // width/channels
#define SS 8192    // sequence
#define NMODE 256  // kept rfft modes
#define KK2 512    // 2*NMODE (re/im interleaved)

typedef __attribute__((ext_vector_type(8))) short short8;
typedef __attribute__((ext_vector_type(4))) float f32x4;

__device__ __forceinline__ float gelu_exact(float v) {
    return 0.5f * v * (1.0f + erff(v * 0.7071067811865476f));
}

__device__ __forceinline__ float b2f(ushort u) {
    return __uint_as_float(((unsigned int)u) << 16);
}
__device__ __forceinline__ ushort f2b(float v) {
    __hip_bfloat16 h = __float2bfloat16(v);  // RNE
    return *(ushort*)&h;
}
__device__ __forceinline__ void split2(float v, ushort& h, ushort& l) {
    h = f2b(v);
    l = f2b(v - b2f(h));
}

// ---------------- DFT basis tables (bf16 hi/lo pairs) ----------------
__global__ void build_T1(ushort* __restrict__ h, ushort* __restrict__ l) {
    int c = blockIdx.x;
    int n = blockIdx.y * 256 + threadIdx.x;
    int k = c >> 1;
    int m = (n * k) & (SS - 1);
    float th = (float)m * (6.283185307179586476925f / (float)SS);
    float s, co;
    sincosf(th, &s, &co);
    float v = (c & 1) ? -s : co;
    ushort hh, ll;
    split2(v, hh, ll);
    h[(size_t)c * SS + n] = hh;
    l[(size_t)c * SS + n] = ll;
}

__global__ void build_T2(ushort* __restrict__ h, ushort* __restrict__ l) {
    int n = blockIdx.x;
    int c = blockIdx.y * 256 + threadIdx.x;
    int k = c >> 1;
    int m = (n * k) & (SS - 1);
    float th = (float)m * (6.283185307179586476925f / (float)SS);
    float s, co;
    sincosf(th, &s, &co);
    float v = (c & 1) ? -s : co;
    ushort hh, ll;
    split2(v, hh, ll);
    h[(size_t)n * KK2 + c] = hh;
    l[(size_t)n * KK2 + c] = ll;
}

__global__ void zero_xf(float* __restrict__ p) {
    size_t i = ((size_t)blockIdx.x * 256 + threadIdx.x) * 4;
    *(float4*)&p[i] = make_float4(0.f, 0.f, 0.f, 0.f);
}

// ---------------- lifting layer (writes split x) ----------------
__global__ void lift_kernel(const float* __restrict__ u, const float* __restrict__ w0,
                            const float* __restrict__ b0, ushort* __restrict__ xh,
                            ushort* __restrict__ xl) {
    int n = blockIdx.x * 256 + threadIdx.x;
    int c = blockIdx.y;
    int b = blockIdx.z;
    float uv = u[b * SS + n];
    float g = (float)n * (1.0f / (float)(SS - 1));
    float v = uv * w0[c] + g * w0[CC + c] + b0[c];
    ushort hh, ll;
    split2(v, hh, ll);
    size_t idx = (size_t)(b * CC + c) * SS + n;
    xh[idx] = hh;
    xl[idx] = ll;
}

// ---------------- forward truncated DFT: split-bf16 MFMA GEMM ----------------
// Xf[4096][512] += X[m][n] * T1[c][n]; K split 8 ways, atomic accumulate.
// LDS layout [4 k-groups][128 rows][8 ushort] (conflict-free, r4-validated);
// staging via VGPRs with loads at loop-top (overlaps previous step's MFMAs).
__global__ __launch_bounds__(256) void dft_mfma(const ushort* __restrict__ xh,
                                                const ushort* __restrict__ xl,
                                                const ushort* __restrict__ t1h,
                                                const ushort* __restrict__ t1l,
                                                float* __restrict__ Xf) {
    __shared__ __align__(16) ushort SM[16384];  // 32 KB pool
    ushort* As_h = SM;
    ushort* As_l = SM + 4096;
    ushort* Bs_h = SM + 8192;
    ushort* Bs_l = SM + 12288;
    const int t = threadIdx.x;
    const int c0 = blockIdx.x * 128;
    const int m0 = blockIdx.y * 128;
    const int kz = blockIdx.z * (SS / 8);
    const int lane = t & 63, w = t >> 6;
    const int wm = (w >> 1) * 64, wn = (w & 1) * 64;
    const int fr = lane & 15, g = lane >> 4;
    const int sr = t >> 1, sh = (t & 1) * 16;  // staging: 2 thr/row, 16 els
    const int g0 = (t & 1) * 2;
    const int d0 = ((g0 + 0) * 128 + sr) * 8;
    const int d1 = ((g0 + 1) * 128 + sr) * 8;

    f32x4 acc[4][4];
#pragma unroll
    for (int i = 0; i < 4; i++)
#pragma unroll
        for (int j = 0; j < 4; j++) acc[i][j] = (f32x4)0.f;

    const size_t arow = (size_t)(m0 + sr) * SS;
    const size_t brow = (size_t)(c0 + sr) * SS;

    for (int kt = kz; kt < kz + SS / 8; kt += 32) {
        const size_t ga = arow + kt + sh;
        const size_t gb = brow + kt + sh;
        short8 a0h = *(const short8*)&xh[ga];
        short8 a1h = *(const short8*)&xh[ga + 8];
        short8 a0l = *(const short8*)&xl[ga];
        short8 a1l = *(const short8*)&xl[ga + 8];
        short8 b0h = *(const short8*)&t1h[gb];
        short8 b1h = *(const short8*)&t1h[gb + 8];
        short8 b0l = *(const short8*)&t1l[gb];
        short8 b1l = *(const short8*)&t1l[gb + 8];
        __syncthreads();
        *(short8*)&As_h[d0] = a0h;
        *(short8*)&As_h[d1] = a1h;
        *(short8*)&As_l[d0] = a0l;
        *(short8*)&As_l[d1] = a1l;
        *(short8*)&Bs_h[d0] = b0h;
        *(short8*)&Bs_h[d1] = b1h;
        *(short8*)&Bs_l[d0] = b0l;
        *(short8*)&Bs_l[d1] = b1l;
        __syncthreads();
        short8 ah[4], al[4];
#pragma unroll
        for (int mt = 0; mt < 4; mt++) {
            int off = (g * 128 + wm + mt * 16 + fr) * 8;
            ah[mt] = *(const short8*)&As_h[off];
            al[mt] = *(const short8*)&As_l[off];
        }
#pragma unroll
        for (int nt = 0; nt < 4; nt++) {
            int off = (g * 128 + wn + nt * 16 + fr) * 8;
            short8 bh = *(const short8*)&Bs_h[off];
            short8 bl = *(const short8*)&Bs_l[off];
#pragma unroll
            for (int mt = 0; mt < 4; mt++) {
                acc[mt][nt] = __builtin_amdgcn_mfma_f32_16x16x32_bf16(ah[mt], bh, acc[mt][nt], 0, 0, 0);
                acc[mt][nt] = __builtin_amdgcn_mfma_f32_16x16x32_bf16(ah[mt], bl, acc[mt][nt], 0, 0, 0);
                acc[mt][nt] = __builtin_amdgcn_mfma_f32_16x16x32_bf16(al[mt], bh, acc[mt][nt], 0, 0, 0);
            }
        }
    }
    const int rr = g * 4;
#pragma unroll
    for (int mt = 0; mt < 4; mt++) {
        int m = m0 + wm + mt * 16 + rr;
#pragma unroll
        for (int nt = 0; nt < 4; nt++) {
            int c = c0 + wn + nt * 16 + fr;
#pragma unroll
            for (int r = 0; r < 4; r++)
                atomicAdd(&Xf[(size_t)(m + r) * KK2 + c], acc[mt][nt][r]);
        }
    }
}

// ---------------- mode mixing (fp32, 2x2 micro-tile, writes split om) --------
__global__ __launch_bounds__(256) void mode_mix(const float* __restrict__ Xf,
                                                const float* __restrict__ swr,
                                                const float* __restrict__ swi,
                                                ushort* __restrict__ omh,
                                                ushort* __restrict__ oml, int l) {
    int k = threadIdx.x;
    int bg = blockIdx.x * 2;
    int og = blockIdx.y * 2;
    float ar[2][2] = {}, ai[2][2] = {};
#pragma unroll 2
    for (int i = 0; i < CC; i++) {
        float2 x0 = *(const float2*)&Xf[((size_t)(bg + 0) * CC + i) * KK2 + 2 * k];
        float2 x1 = *(const float2*)&Xf[((size_t)(bg + 1) * CC + i) * KK2 + 2 * k];
        size_t wb = ((size_t)(l * CC + i) * CC + og) * NMODE + k;
        float wr0 = swr[wb], wi0 = swi[wb];
        float wr1 = swr[wb + NMODE], wi1 = swi[wb + NMODE];
        ar[0][0] += x0.x * wr0 - x0.y * wi0;
        ai[0][0] += x0.x * wi0 + x0.y * wr0;
        ar[0][1] += x0.x * wr1 - x0.y * wi1;
        ai[0][1] += x0.x * wi1 + x0.y * wr1;
        ar[1][0] += x1.x * wr0 - x1.y * wi0;
        ai[1][0] += x1.x * wi0 + x1.y * wr0;
        ar[1][1] += x1.x * wr1 - x1.y * wi1;
        ai[1][1] += x1.x * wi1 + x1.y * wr1;
    }
    float ck = (k == 0) ? (1.0f / (float)SS) : (2.0f / (float)SS);
#pragma unroll
    for (int b2 = 0; b2 < 2; b2++)
#pragma unroll
        for (int oo = 0; oo < 2; oo++) {
            float re = ar[b2][oo] * ck;
            float im = ai[b2][oo] * ck;
            ushort hr, lr2, hi2, li2;
            split2(re, hr, lr2);
            split2(im, hi2, li2);
            size_t base = ((size_t)(bg + b2) * CC + og + oo) * KK2 + 2 * k;
            *(ushort2*)&omh[base] = make_ushort2(hr, hi2);
            *(ushort2*)&oml[base] = make_ushort2(lr2, li2);
        }
}

// ---------------- inverse DFT + pointwise + bias + gelu (MFMA, in place) ----
// Phase 1: K=512 modes via LDS (conflict-free layout, VGPR-staged pipeline).
// Phase 2: K=64 channels; step-0 B gathered into VGPRs at kernel ENTRY
// (latency hidden behind phase 1), step-1 gathered behind step-0 compute.
__global__ __launch_bounds__(256) void inv_mfma(const ushort* __restrict__ omh,
                                                const ushort* __restrict__ oml,
                                                const ushort* __restrict__ t2h,
                                                const ushort* __restrict__ t2l,
                                                const float* __restrict__ pww,
                                                const float* __restrict__ pwb,
                                                ushort* __restrict__ xh,
                                                ushort* __restrict__ xl, int l,
                                                int gel) {
    __shared__ __align__(16) ushort SM[16384];  // 32 KB pool
    ushort* As_h = SM;
    ushort* As_l = SM + 4096;
    ushort* Bs_h = SM + 8192;
    ushort* Bs_l = SM + 12288;
    const int t = threadIdx.x;
    const int n0 = blockIdx.x * 128;
    const int row0 = blockIdx.y * 128;
    const int lane = t & 63, w = t >> 6;
    const int wm = (w >> 1) * 64, wn = (w & 1) * 64;
    const int fr = lane & 15, g = lane >> 4;
    const int sr = t >> 1, sh = (t & 1) * 16;
    const int g0 = (t & 1) * 2;
    const int d0 = ((g0 + 0) * 128 + sr) * 8;
    const int d1 = ((g0 + 1) * 128 + sr) * 8;
    const int xrowb = row0 + wm;  // this wave's batch base row

    // ---- park phase-2 step-0 B fragments (issued now, used after phase 1)
    short8 pk_h[4], pk_l[4];
#pragma unroll
    for (int nt = 0; nt < 4; nt++) {
        int ncol = n0 + wn + nt * 16 + fr;
#pragma unroll
        for (int j = 0; j < 8; j++) {
            size_t gxi = (size_t)(xrowb + g * 8 + j) * SS + ncol;
            pk_h[nt][j] = (short)xh[gxi];
            pk_l[nt][j] = (short)xl[gxi];
        }
    }

    f32x4 acc[4][4];
#pragma unroll
    for (int i = 0; i < 4; i++)
#pragma unroll
        for (int j = 0; j < 4; j++) acc[i][j] = (f32x4)0.f;

    const size_t arow = (size_t)(row0 + sr) * KK2;
    const size_t brow = (size_t)(n0 + sr) * KK2;

    // phase 1: modes (16 steps of K=32)
    for (int kt = 0; kt < KK2; kt += 32) {
        const size_t ga = arow + kt + sh;
        const size_t gb = brow + kt + sh;
        short8 a0h = *(const short8*)&omh[ga];
        short8 a1h = *(const short8*)&omh[ga + 8];
        short8 a0l = *(const short8*)&oml[ga];
        short8 a1l = *(const short8*)&oml[ga + 8];
        short8 b0h = *(const short8*)&t2h[gb];
        short8 b1h = *(const short8*)&t2h[gb + 8];
        short8 b0l = *(const short8*)&t2l[gb];
        short8 b1l = *(const short8*)&t2l[gb + 8];
        __syncthreads();
        *(short8*)&As_h[d0] = a0h;
        *(short8*)&As_h[d1] = a1h;
        *(short8*)&As_l[d0] = a0l;
        *(short8*)&As_l[d1] = a1l;
        *(short8*)&Bs_h[d0] = b0h;
        *(short8*)&Bs_h[d1] = b1h;
        *(short8*)&Bs_l[d0] = b0l;
        *(short8*)&Bs_l[d1] = b1l;
        __syncthreads();
        short8 ah[4], al[4];
#pragma unroll
        for (int mt = 0; mt < 4; mt++) {
            int off = (g * 128 + wm + mt * 16 + fr) * 8;
            ah[mt] = *(const short8*)&As_h[off];
            al[mt] = *(const short8*)&As_l[off];
        }
#pragma unroll
        for (int nt = 0; nt < 4; nt++) {
            int off = (g * 128 + wn + nt * 16 + fr) * 8;
            short8 bh = *(const short8*)&Bs_h[off];
            short8 bl = *(const short8*)&Bs_l[off];
#pragma unroll
            for (int mt = 0; mt < 4; mt++) {
                acc[mt][nt] = __builtin_amdgcn_mfma_f32_16x16x32_bf16(ah[mt], bh, acc[mt][nt], 0, 0, 0);
                acc[mt][nt] = __builtin_amdgcn_mfma_f32_16x16x32_bf16(ah[mt], bl, acc[mt][nt], 0, 0, 0);
                acc[mt][nt] = __builtin_amdgcn_mfma_f32_16x16x32_bf16(al[mt], bh, acc[mt][nt], 0, 0, 0);
            }
        }
    }
    // phase 2: pointwise conv (2 steps of 32 channels; B from VGPRs/global)
#pragma unroll
    for (int s = 0; s < 2; s++) {
        const int i0 = s * 32;
        short8 pah[4], pal[4];
#pragma unroll
        for (int mt = 0; mt < 4; mt++) {
            int o = mt * 16 + fr;
            const float* pp = &pww[(size_t)(l * CC + o) * CC + i0 + g * 8];
            float4 pa = *(const float4*)pp;
            float4 pb = *(const float4*)(pp + 4);
            float pv[8] = {pa.x, pa.y, pa.z, pa.w, pb.x, pb.y, pb.z, pb.w};
#pragma unroll
            for (int e = 0; e < 8; e++) {
                ushort h2, l2;
                split2(pv[e], h2, l2);
                pah[mt][e] = (short)h2;
                pal[mt][e] = (short)l2;
            }
        }
#pragma unroll
        for (int nt = 0; nt < 4; nt++) {
            short8 bh, bl;
            if (s == 0) {
                bh = pk_h[nt];
                bl = pk_l[nt];
            } else {
                int ncol = n0 + wn + nt * 16 + fr;
#pragma unroll
                for (int j = 0; j < 8; j++) {
                    size_t gxi = (size_t)(xrowb + i0 + g * 8 + j) * SS + ncol;
                    bh[j] = (short)xh[gxi];
                    bl[j] = (short)xl[gxi];
                }
            }
#pragma unroll
            for (int mt = 0; mt < 4; mt++) {
                acc[mt][nt] = __builtin_amdgcn_mfma_f32_16x16x32_bf16(pah[mt], bh, acc[mt][nt], 0, 0, 0);
                acc[mt][nt] = __builtin_amdgcn_mfma_f32_16x16x32_bf16(pah[mt], bl, acc[mt][nt], 0, 0, 0);
                acc[mt][nt] = __builtin_amdgcn_mfma_f32_16x16x32_bf16(pal[mt], bh, acc[mt][nt], 0, 0, 0);
            }
        }
    }
    // epilogue: bias + gelu + split-store (in place; block owns rows x cols)
    const int rr = g * 4;
#pragma unroll
    for (int mt = 0; mt < 4; mt++) {
        int rl = wm + mt * 16 + rr;
#pragma unroll
        for (int r = 0; r < 4; r++) {
            int o = (rl + r) & 63;
            float bias = pwb[l * CC + o];
#pragma unroll
            for (int nt = 0; nt < 4; nt++) {
                int n = n0 + wn + nt * 16 + fr;
                float v = acc[mt][nt][r] + bias;
                if (gel) v = gelu_exact(v);
                ushort h2, l2;
                split2(v, h2, l2);
                size_t gg = (size_t)(row0 + rl + r) * SS + n;
                xh[gg] = h2;
                xl[gg] = l2;
            }
        }
    }
}

// ---------------- projection head ----------------
__global__ __launch_bounds__(256) void head_kernel(const ushort* __restrict__ xh,
                                                   const ushort* __restrict__ xl,
                                                   const float* __restrict__ w1,
                                                   const float* __restrict__ b1,
                                                   const float* __restrict__ w2,
                                                   const float* __restrict__ b2,
                                                   float* __restrict__ out) {
    __shared__ float Xs[64][64];
    __shared__ float W1s[64][128];
    __shared__ float part[4][64];
    int b = blockIdx.y;
    int n0 = blockIdx.x * 64;
    int tid = threadIdx.x;
    {
        int c = tid >> 2, nq = tid & 3;
        size_t gx = (size_t)(b * CC + c) * SS + n0 + nq * 16;
        short8 hA = *(const short8*)&xh[gx];
        short8 hB = *(const short8*)&xh[gx + 8];
        short8 lA = *(const short8*)&xl[gx];
        short8 lB = *(const short8*)&xl[gx + 8];
#pragma unroll
        for (int e = 0; e < 8; e++) {
            Xs[c][nq * 16 + e] = b2f((ushort)hA[e]) + b2f((ushort)lA[e]);
            Xs[c][nq * 16 + 8 + e] = b2f((ushort)hB[e]) + b2f((ushort)lB[e]);
        }
    }
    float* w1flat = &W1s[0][0];
#pragma unroll
    for (int q = 0; q < 8; q++) {
        int off = q * 1024 + tid * 4;
        *(float4*)&w1flat[off] = *(const float4*)&w1[off];
    }
    __syncthreads();
    int nn = tid & 63, jg = tid >> 6;
    float h[32];
#pragma unroll
    for (int jj = 0; jj < 32; jj++) h[jj] = b1[jg * 32 + jj];
    for (int c = 0; c < 64; c++) {
        float xv = Xs[c][nn];
#pragma unroll
        for (int jj = 0; jj < 32; jj++)
            h[jj] = fmaf(xv, W1s[c][jg * 32 + jj], h[jj]);
    }
    float p = 0.f;
#pragma unroll
    for (int jj = 0; jj < 32; jj++)
        p = fmaf(gelu_exact(h[jj]), w2[jg * 32 + jj], p);
    part[jg][nn] = p;
    __syncthreads();
    if (tid < 64) {
        float v = part[0][tid] + part[1][tid] + part[2][tid] + part[3][tid] + b2[0];
        out[b * SS + n0 + tid] = v;
    }
}

extern "C" void kernel_launch(void* const* d_in, const int* in_sizes, int n_in,
                              void* d_out, int out_size, void* d_ws, size_t ws_size,
                              hipStream_t stream) {
    (void)in_sizes; (void)n_in; (void)out_size; (void)ws_size;
    const float* u = (const float*)d_in[0];
    const float* fc0_w = (const float*)d_in[1];
    const float* fc0_b = (const float*)d_in[2];
    const float* sw_r = (const float*)d_in[3];
    const float* sw_i = (const float*)d_in[4];
    const float* pw_w = (const float*)d_in[5];
    const float* pw_b = (const float*)d_in[6];
    const float* fc1_w = (const float*)d_in[7];
    const float* fc1_b = (const float*)d_in[8];
    const float* fc2_w = (const float*)d_in[9];
    const float* fc2_b = (const float*)d_in[10];
    float* out = (float*)d_out;

    // workspace layout (total = 184,549,376 B)
    char* ws = (char*)d_ws;
    ushort* xh = (ushort*)ws;                        // 33,554,432 els
    ushort* xl = (ushort*)(ws + 67108864);           // 33,554,432
    ushort* t1h = (ushort*)(ws + 134217728);         // [512][8192]
    ushort* t1l = (ushort*)(ws + 142606336);
    ushort* t2h = (ushort*)(ws + 150994944);         // [8192][512]
    ushort* t2l = (ushort*)(ws + 159383552);
    ushort* omh = (ushort*)(ws + 167772160);         // [4096][512]
    ushort* oml = (ushort*)(ws + 171966464);
    float* Xf = (float*)(ws + 176160768);            // [4096][512] fp32

    build_T1<<<dim3(KK2, SS / 256), 256, 0, stream>>>(t1h, t1l);
    build_T2<<<dim3(SS, KK2 / 256), 256, 0, stream>>>(t2h, t2l);
    lift_kernel<<<dim3(SS / 256, CC, BB), 256, 0, stream>>>(u, fc0_w, fc0_b, xh, xl);

    for (int l = 0; l < 4; l++) {
        zero_xf<<<dim3(2048), 256, 0, stream>>>(Xf);
        dft_mfma<<<dim3(KK2 / 128, (BB * CC) / 128, 8), 256, 0, stream>>>(
            xh, xl, t1h, t1l, Xf);
        mode_mix<<<dim3(BB / 2, CC / 2), 256, 0, stream>>>(Xf, sw_r, sw_i, omh, oml, l);
        inv_mfma<<<dim3(SS / 128, BB / 2), 256, 0, stream>>>(
            omh, oml, t2h, t2l, pw_w, pw_b, xh, xl, l, (l < 3) ? 1 : 0);
    }
    head_kernel<<<dim3(SS / 64, BB), 256, 0, stream>>>(xh, xl, fc1_w, fc1_b, fc2_w,
                                                       fc2_b, out);
}

// Round 6
// 1564.011 us; speedup vs baseline: 1.3514x; 1.2045x over previous
//
#include <hip/hip_runtime.h>
#include <hip/hip_bf16.h>
#include <math.h>

#define BB 64      // batch
#define CC 64      // width/channels
#define SS 8192    // sequence
#define NMODE 256  // kept rfft modes
#define KK2 512    // 2*NMODE (re/im interleaved)

typedef __attribute__((ext_vector_type(8))) short short8;
typedef __attribute__((ext_vector_type(4))) float f32x4;

__device__ __forceinline__ float gelu_exact(float v) {
    return 0.5f * v * (1.0f + erff(v * 0.7071067811865476f));
}

__device__ __forceinline__ float b2f(ushort u) {
    return __uint_as_float(((unsigned int)u) << 16);
}
__device__ __forceinline__ ushort f2b(float v) {
    __hip_bfloat16 h = __float2bfloat16(v);  // RNE
    return *(ushort*)&h;
}
__device__ __forceinline__ void split2(float v, ushort& h, ushort& l) {
    h = f2b(v);
    l = f2b(v - b2f(h));
}

// ---------------- DFT basis tables (bf16 hi/lo pairs) ----------------
__global__ void build_T1(ushort* __restrict__ h, ushort* __restrict__ l) {
    int c = blockIdx.x;
    int n = blockIdx.y * 256 + threadIdx.x;
    int k = c >> 1;
    int m = (n * k) & (SS - 1);
    float th = (float)m * (6.283185307179586476925f / (float)SS);
    float s, co;
    sincosf(th, &s, &co);
    float v = (c & 1) ? -s : co;
    ushort hh, ll;
    split2(v, hh, ll);
    h[(size_t)c * SS + n] = hh;
    l[(size_t)c * SS + n] = ll;
}

__global__ void build_T2(ushort* __restrict__ h, ushort* __restrict__ l) {
    int n = blockIdx.x;
    int c = blockIdx.y * 256 + threadIdx.x;
    int k = c >> 1;
    int m = (n * k) & (SS - 1);
    float th = (float)m * (6.283185307179586476925f / (float)SS);
    float s, co;
    sincosf(th, &s, &co);
    float v = (c & 1) ? -s : co;
    ushort hh, ll;
    split2(v, hh, ll);
    h[(size_t)n * KK2 + c] = hh;
    l[(size_t)n * KK2 + c] = ll;
}

__global__ void zero_xf(float* __restrict__ p) {
    size_t i = ((size_t)blockIdx.x * 256 + threadIdx.x) * 4;
    *(float4*)&p[i] = make_float4(0.f, 0.f, 0.f, 0.f);
}

// ---------------- lifting layer (writes split x) ----------------
__global__ void lift_kernel(const float* __restrict__ u, const float* __restrict__ w0,
                            const float* __restrict__ b0, ushort* __restrict__ xh,
                            ushort* __restrict__ xl) {
    int n = blockIdx.x * 256 + threadIdx.x;
    int c = blockIdx.y;
    int b = blockIdx.z;
    float uv = u[b * SS + n];
    float g = (float)n * (1.0f / (float)(SS - 1));
    float v = uv * w0[c] + g * w0[CC + c] + b0[c];
    ushort hh, ll;
    split2(v, hh, ll);
    size_t idx = (size_t)(b * CC + c) * SS + n;
    xh[idx] = hh;
    xl[idx] = ll;
}

// ---------------- forward truncated DFT: split-bf16 MFMA GEMM ----------------
// Xf[4096][512] += X[m][n] * T1[c][n]; K split 4 ways, atomic accumulate.
// 1-D grid with XCD-aware decode: the 4 blocks sharing an A-tile (same y,z)
// have linear ids differing by 8 -> same XCD -> A fetched once per XCD.
// Register double-buffer: next tile's global loads issue after this tile's
// LDS write, covered by 48 MFMAs + frag reads.
__global__ __launch_bounds__(256) void dft_mfma(const ushort* __restrict__ xh,
                                                const ushort* __restrict__ xl,
                                                const ushort* __restrict__ t1h,
                                                const ushort* __restrict__ t1l,
                                                float* __restrict__ Xf) {
    __shared__ __align__(16) ushort SM[16384];  // 32 KB pool
    ushort* As_h = SM;
    ushort* As_l = SM + 4096;
    ushort* Bs_h = SM + 8192;
    ushort* Bs_l = SM + 12288;
    const int t = threadIdx.x;
    const int L = blockIdx.x;            // 512 blocks
    const int gq = L >> 5, j = L & 31;
    const int c0 = (j >> 3) * 128;                    // 4 c-tiles
    const int m0 = ((gq & 3) * 8 + (j & 7)) * 128;    // 32 m-tiles
    const int kz = (gq >> 2) * (SS / 4);              // 4 k-splits
    const int lane = t & 63, w = t >> 6;
    const int wm = (w >> 1) * 64, wn = (w & 1) * 64;
    const int fr = lane & 15, g = lane >> 4;
    const int sr = t >> 1, sh = (t & 1) * 16;  // staging: 2 thr/row, 16 els
    const int g0 = (t & 1) * 2;
    const int d0 = ((g0 + 0) * 128 + sr) * 8;
    const int d1 = ((g0 + 1) * 128 + sr) * 8;

    f32x4 acc[4][4];
#pragma unroll
    for (int i = 0; i < 4; i++)
#pragma unroll
        for (int jj = 0; jj < 4; jj++) acc[i][jj] = (f32x4)0.f;

    const size_t arow = (size_t)(m0 + sr) * SS;
    const size_t brow = (size_t)(c0 + sr) * SS;
    const int kend = kz + SS / 4;

    short8 a0h, a1h, a0l, a1l, b0h, b1h, b0l, b1l;
    {
        const size_t ga = arow + kz + sh;
        const size_t gb = brow + kz + sh;
        a0h = *(const short8*)&xh[ga];
        a1h = *(const short8*)&xh[ga + 8];
        a0l = *(const short8*)&xl[ga];
        a1l = *(const short8*)&xl[ga + 8];
        b0h = *(const short8*)&t1h[gb];
        b1h = *(const short8*)&t1h[gb + 8];
        b0l = *(const short8*)&t1l[gb];
        b1l = *(const short8*)&t1l[gb + 8];
    }
    for (int kt = kz; kt < kend; kt += 32) {
        __syncthreads();
        *(short8*)&As_h[d0] = a0h;
        *(short8*)&As_h[d1] = a1h;
        *(short8*)&As_l[d0] = a0l;
        *(short8*)&As_l[d1] = a1l;
        *(short8*)&Bs_h[d0] = b0h;
        *(short8*)&Bs_h[d1] = b1h;
        *(short8*)&Bs_l[d0] = b0l;
        *(short8*)&Bs_l[d1] = b1l;
        __syncthreads();
        // prefetch next step (clamped reload of tile 0 on the last step)
        const int ktn = (kt + 32 < kend) ? kt + 32 : kz;
        const size_t ga = arow + ktn + sh;
        const size_t gb = brow + ktn + sh;
        a0h = *(const short8*)&xh[ga];
        a1h = *(const short8*)&xh[ga + 8];
        a0l = *(const short8*)&xl[ga];
        a1l = *(const short8*)&xl[ga + 8];
        b0h = *(const short8*)&t1h[gb];
        b1h = *(const short8*)&t1h[gb + 8];
        b0l = *(const short8*)&t1l[gb];
        b1l = *(const short8*)&t1l[gb + 8];
        short8 ah[4], al[4];
#pragma unroll
        for (int mt = 0; mt < 4; mt++) {
            int off = (g * 128 + wm + mt * 16 + fr) * 8;
            ah[mt] = *(const short8*)&As_h[off];
            al[mt] = *(const short8*)&As_l[off];
        }
#pragma unroll
        for (int nt = 0; nt < 4; nt++) {
            int off = (g * 128 + wn + nt * 16 + fr) * 8;
            short8 bh = *(const short8*)&Bs_h[off];
            short8 bl = *(const short8*)&Bs_l[off];
#pragma unroll
            for (int mt = 0; mt < 4; mt++) {
                acc[mt][nt] = __builtin_amdgcn_mfma_f32_16x16x32_bf16(ah[mt], bh, acc[mt][nt], 0, 0, 0);
                acc[mt][nt] = __builtin_amdgcn_mfma_f32_16x16x32_bf16(ah[mt], bl, acc[mt][nt], 0, 0, 0);
                acc[mt][nt] = __builtin_amdgcn_mfma_f32_16x16x32_bf16(al[mt], bh, acc[mt][nt], 0, 0, 0);
            }
        }
    }
    const int rr = g * 4;
#pragma unroll
    for (int mt = 0; mt < 4; mt++) {
        int m = m0 + wm + mt * 16 + rr;
#pragma unroll
        for (int nt = 0; nt < 4; nt++) {
            int c = c0 + wn + nt * 16 + fr;
#pragma unroll
            for (int r = 0; r < 4; r++)
                atomicAdd(&Xf[(size_t)(m + r) * KK2 + c], acc[mt][nt][r]);
        }
    }
}

// ---------------- mode mixing (fp32, 2x2 micro-tile, writes split om) --------
__global__ __launch_bounds__(256) void mode_mix(const float* __restrict__ Xf,
                                                const float* __restrict__ swr,
                                                const float* __restrict__ swi,
                                                ushort* __restrict__ omh,
                                                ushort* __restrict__ oml, int l) {
    int k = threadIdx.x;
    int bg = blockIdx.x * 2;
    int og = blockIdx.y * 2;
    float ar[2][2] = {}, ai[2][2] = {};
#pragma unroll 2
    for (int i = 0; i < CC; i++) {
        float2 x0 = *(const float2*)&Xf[((size_t)(bg + 0) * CC + i) * KK2 + 2 * k];
        float2 x1 = *(const float2*)&Xf[((size_t)(bg + 1) * CC + i) * KK2 + 2 * k];
        size_t wb = ((size_t)(l * CC + i) * CC + og) * NMODE + k;
        float wr0 = swr[wb], wi0 = swi[wb];
        float wr1 = swr[wb + NMODE], wi1 = swi[wb + NMODE];
        ar[0][0] += x0.x * wr0 - x0.y * wi0;
        ai[0][0] += x0.x * wi0 + x0.y * wr0;
        ar[0][1] += x0.x * wr1 - x0.y * wi1;
        ai[0][1] += x0.x * wi1 + x0.y * wr1;
        ar[1][0] += x1.x * wr0 - x1.y * wi0;
        ai[1][0] += x1.x * wi0 + x1.y * wr0;
        ar[1][1] += x1.x * wr1 - x1.y * wi1;
        ai[1][1] += x1.x * wi1 + x1.y * wr1;
    }
    float ck = (k == 0) ? (1.0f / (float)SS) : (2.0f / (float)SS);
#pragma unroll
    for (int b2 = 0; b2 < 2; b2++)
#pragma unroll
        for (int oo = 0; oo < 2; oo++) {
            float re = ar[b2][oo] * ck;
            float im = ai[b2][oo] * ck;
            ushort hr, lr2, hi2, li2;
            split2(re, hr, lr2);
            split2(im, hi2, li2);
            size_t base = ((size_t)(bg + b2) * CC + og + oo) * KK2 + 2 * k;
            *(ushort2*)&omh[base] = make_ushort2(hr, hi2);
            *(ushort2*)&oml[base] = make_ushort2(lr2, li2);
        }
}

// ---------------- inverse DFT + pointwise + bias + gelu (MFMA, in place) ----
// Phase 1: K=512 modes via LDS with register double-buffer prefetch.
// Phase 2: K=64 channels; step-0 B gathered into VGPRs at kernel entry.
__global__ __launch_bounds__(256) void inv_mfma(const ushort* __restrict__ omh,
                                                const ushort* __restrict__ oml,
                                                const ushort* __restrict__ t2h,
                                                const ushort* __restrict__ t2l,
                                                const float* __restrict__ pww,
                                                const float* __restrict__ pwb,
                                                ushort* __restrict__ xh,
                                                ushort* __restrict__ xl, int l,
                                                int gel) {
    __shared__ __align__(16) ushort SM[16384];  // 32 KB pool
    ushort* As_h = SM;
    ushort* As_l = SM + 4096;
    ushort* Bs_h = SM + 8192;
    ushort* Bs_l = SM + 12288;
    const int t = threadIdx.x;
    const int n0 = blockIdx.x * 128;
    const int row0 = blockIdx.y * 128;
    const int lane = t & 63, w = t >> 6;
    const int wm = (w >> 1) * 64, wn = (w & 1) * 64;
    const int fr = lane & 15, g = lane >> 4;
    const int sr = t >> 1, sh = (t & 1) * 16;
    const int g0 = (t & 1) * 2;
    const int d0 = ((g0 + 0) * 128 + sr) * 8;
    const int d1 = ((g0 + 1) * 128 + sr) * 8;
    const int xrowb = row0 + wm;  // this wave's batch base row

    // ---- park phase-2 step-0 B fragments (issued now, used after phase 1)
    short8 pk_h[4], pk_l[4];
#pragma unroll
    for (int nt = 0; nt < 4; nt++) {
        int ncol = n0 + wn + nt * 16 + fr;
#pragma unroll
        for (int jj = 0; jj < 8; jj++) {
            size_t gxi = (size_t)(xrowb + g * 8 + jj) * SS + ncol;
            pk_h[nt][jj] = (short)xh[gxi];
            pk_l[nt][jj] = (short)xl[gxi];
        }
    }

    f32x4 acc[4][4];
#pragma unroll
    for (int i = 0; i < 4; i++)
#pragma unroll
        for (int jj = 0; jj < 4; jj++) acc[i][jj] = (f32x4)0.f;

    const size_t arow = (size_t)(row0 + sr) * KK2;
    const size_t brow = (size_t)(n0 + sr) * KK2;

    short8 a0h, a1h, a0l, a1l, b0h, b1h, b0l, b1l;
    {
        const size_t ga = arow + sh;
        const size_t gb = brow + sh;
        a0h = *(const short8*)&omh[ga];
        a1h = *(const short8*)&omh[ga + 8];
        a0l = *(const short8*)&oml[ga];
        a1l = *(const short8*)&oml[ga + 8];
        b0h = *(const short8*)&t2h[gb];
        b1h = *(const short8*)&t2h[gb + 8];
        b0l = *(const short8*)&t2l[gb];
        b1l = *(const short8*)&t2l[gb + 8];
    }
    // phase 1: modes (16 steps of K=32)
    for (int kt = 0; kt < KK2; kt += 32) {
        __syncthreads();
        *(short8*)&As_h[d0] = a0h;
        *(short8*)&As_h[d1] = a1h;
        *(short8*)&As_l[d0] = a0l;
        *(short8*)&As_l[d1] = a1l;
        *(short8*)&Bs_h[d0] = b0h;
        *(short8*)&Bs_h[d1] = b1h;
        *(short8*)&Bs_l[d0] = b0l;
        *(short8*)&Bs_l[d1] = b1l;
        __syncthreads();
        const int ktn = (kt + 32 < KK2) ? kt + 32 : 0;
        const size_t ga = arow + ktn + sh;
        const size_t gb = brow + ktn + sh;
        a0h = *(const short8*)&omh[ga];
        a1h = *(const short8*)&omh[ga + 8];
        a0l = *(const short8*)&oml[ga];
        a1l = *(const short8*)&oml[ga + 8];
        b0h = *(const short8*)&t2h[gb];
        b1h = *(const short8*)&t2h[gb + 8];
        b0l = *(const short8*)&t2l[gb];
        b1l = *(const short8*)&t2l[gb + 8];
        short8 ah[4], al[4];
#pragma unroll
        for (int mt = 0; mt < 4; mt++) {
            int off = (g * 128 + wm + mt * 16 + fr) * 8;
            ah[mt] = *(const short8*)&As_h[off];
            al[mt] = *(const short8*)&As_l[off];
        }
#pragma unroll
        for (int nt = 0; nt < 4; nt++) {
            int off = (g * 128 + wn + nt * 16 + fr) * 8;
            short8 bh = *(const short8*)&Bs_h[off];
            short8 bl = *(const short8*)&Bs_l[off];
#pragma unroll
            for (int mt = 0; mt < 4; mt++) {
                acc[mt][nt] = __builtin_amdgcn_mfma_f32_16x16x32_bf16(ah[mt], bh, acc[mt][nt], 0, 0, 0);
                acc[mt][nt] = __builtin_amdgcn_mfma_f32_16x16x32_bf16(ah[mt], bl, acc[mt][nt], 0, 0, 0);
                acc[mt][nt] = __builtin_amdgcn_mfma_f32_16x16x32_bf16(al[mt], bh, acc[mt][nt], 0, 0, 0);
            }
        }
    }
    // phase 2: pointwise conv (2 steps of 32 channels; B from VGPRs/global)
#pragma unroll
    for (int s = 0; s < 2; s++) {
        const int i0 = s * 32;
        short8 pah[4], pal[4];
#pragma unroll
        for (int mt = 0; mt < 4; mt++) {
            int o = mt * 16 + fr;
            const float* pp = &pww[(size_t)(l * CC + o) * CC + i0 + g * 8];
            float4 pa = *(const float4*)pp;
            float4 pb = *(const float4*)(pp + 4);
            float pv[8] = {pa.x, pa.y, pa.z, pa.w, pb.x, pb.y, pb.z, pb.w};
#pragma unroll
            for (int e = 0; e < 8; e++) {
                ushort h2, l2;
                split2(pv[e], h2, l2);
                pah[mt][e] = (short)h2;
                pal[mt][e] = (short)l2;
            }
        }
#pragma unroll
        for (int nt = 0; nt < 4; nt++) {
            short8 bh, bl;
            if (s == 0) {
                bh = pk_h[nt];
                bl = pk_l[nt];
            } else {
                int ncol = n0 + wn + nt * 16 + fr;
#pragma unroll
                for (int jj = 0; jj < 8; jj++) {
                    size_t gxi = (size_t)(xrowb + i0 + g * 8 + jj) * SS + ncol;
                    bh[jj] = (short)xh[gxi];
                    bl[jj] = (short)xl[gxi];
                }
            }
#pragma unroll
            for (int mt = 0; mt < 4; mt++) {
                acc[mt][nt] = __builtin_amdgcn_mfma_f32_16x16x32_bf16(pah[mt], bh, acc[mt][nt], 0, 0, 0);
                acc[mt][nt] = __builtin_amdgcn_mfma_f32_16x16x32_bf16(pah[mt], bl, acc[mt][nt], 0, 0, 0);
                acc[mt][nt] = __builtin_amdgcn_mfma_f32_16x16x32_bf16(pal[mt], bh, acc[mt][nt], 0, 0, 0);
            }
        }
    }
    // epilogue: bias + gelu + split-store (in place; block owns rows x cols)
    const int rr = g * 4;
#pragma unroll
    for (int mt = 0; mt < 4; mt++) {
        int rl = wm + mt * 16 + rr;
#pragma unroll
        for (int r = 0; r < 4; r++) {
            int o = (rl + r) & 63;
            float bias = pwb[l * CC + o];
#pragma unroll
            for (int nt = 0; nt < 4; nt++) {
                int n = n0 + wn + nt * 16 + fr;
                float v = acc[mt][nt][r] + bias;
                if (gel) v = gelu_exact(v);
                ushort h2, l2;
                split2(v, h2, l2);
                size_t gg = (size_t)(row0 + rl + r) * SS + n;
                xh[gg] = h2;
                xl[gg] = l2;
            }
        }
    }
}

// ---------------- projection head ----------------
__global__ __launch_bounds__(256) void head_kernel(const ushort* __restrict__ xh,
                                                   const ushort* __restrict__ xl,
                                                   const float* __restrict__ w1,
                                                   const float* __restrict__ b1,
                                                   const float* __restrict__ w2,
                                                   const float* __restrict__ b2,
                                                   float* __restrict__ out) {
    __shared__ float Xs[64][64];
    __shared__ float W1s[64][128];
    __shared__ float part[4][64];
    int b = blockIdx.y;
    int n0 = blockIdx.x * 64;
    int tid = threadIdx.x;
    {
        int c = tid >> 2, nq = tid & 3;
        size_t gx = (size_t)(b * CC + c) * SS + n0 + nq * 16;
        short8 hA = *(const short8*)&xh[gx];
        short8 hB = *(const short8*)&xh[gx + 8];
        short8 lA = *(const short8*)&xl[gx];
        short8 lB = *(const short8*)&xl[gx + 8];
#pragma unroll
        for (int e = 0; e < 8; e++) {
            Xs[c][nq * 16 + e] = b2f((ushort)hA[e]) + b2f((ushort)lA[e]);
            Xs[c][nq * 16 + 8 + e] = b2f((ushort)hB[e]) + b2f((ushort)lB[e]);
        }
    }
    float* w1flat = &W1s[0][0];
#pragma unroll
    for (int q = 0; q < 8; q++) {
        int off = q * 1024 + tid * 4;
        *(float4*)&w1flat[off] = *(const float4*)&w1[off];
    }
    __syncthreads();
    int nn = tid & 63, jg = tid >> 6;
    float h[32];
#pragma unroll
    for (int jj = 0; jj < 32; jj++) h[jj] = b1[jg * 32 + jj];
    for (int c = 0; c < 64; c++) {
        float xv = Xs[c][nn];
#pragma unroll
        for (int jj = 0; jj < 32; jj++)
            h[jj] = fmaf(xv, W1s[c][jg * 32 + jj], h[jj]);
    }
    float p = 0.f;
#pragma unroll
    for (int jj = 0; jj < 32; jj++)
        p = fmaf(gelu_exact(h[jj]), w2[jg * 32 + jj], p);
    part[jg][nn] = p;
    __syncthreads();
    if (tid < 64) {
        float v = part[0][tid] + part[1][tid] + part[2][tid] + part[3][tid] + b2[0];
        out[b * SS + n0 + tid] = v;
    }
}

extern "C" void kernel_launch(void* const* d_in, const int* in_sizes, int n_in,
                              void* d_out, int out_size, void* d_ws, size_t ws_size,
                              hipStream_t stream) {
    (void)in_sizes; (void)n_in; (void)out_size; (void)ws_size;
    const float* u = (const float*)d_in[0];
    const float* fc0_w = (const float*)d_in[1];
    const float* fc0_b = (const float*)d_in[2];
    const float* sw_r = (const float*)d_in[3];
    const float* sw_i = (const float*)d_in[4];
    const float* pw_w = (const float*)d_in[5];
    const float* pw_b = (const float*)d_in[6];
    const float* fc1_w = (const float*)d_in[7];
    const float* fc1_b = (const float*)d_in[8];
    const float* fc2_w = (const float*)d_in[9];
    const float* fc2_b = (const float*)d_in[10];
    float* out = (float*)d_out;

    // workspace layout (total = 184,549,376 B)
    char* ws = (char*)d_ws;
    ushort* xh = (ushort*)ws;                        // 33,554,432 els
    ushort* xl = (ushort*)(ws + 67108864);           // 33,554,432
    ushort* t1h = (ushort*)(ws + 134217728);         // [512][8192]
    ushort* t1l = (ushort*)(ws + 142606336);
    ushort* t2h = (ushort*)(ws + 150994944);         // [8192][512]
    ushort* t2l = (ushort*)(ws + 159383552);
    ushort* omh = (ushort*)(ws + 167772160);         // [4096][512]
    ushort* oml = (ushort*)(ws + 171966464);
    float* Xf = (float*)(ws + 176160768);            // [4096][512] fp32

    build_T1<<<dim3(KK2, SS / 256), 256, 0, stream>>>(t1h, t1l);
    build_T2<<<dim3(SS, KK2 / 256), 256, 0, stream>>>(t2h, t2l);
    lift_kernel<<<dim3(SS / 256, CC, BB), 256, 0, stream>>>(u, fc0_w, fc0_b, xh, xl);

    for (int l = 0; l < 4; l++) {
        zero_xf<<<dim3(2048), 256, 0, stream>>>(Xf);
        dft_mfma<<<dim3(512), 256, 0, stream>>>(xh, xl, t1h, t1l, Xf);
        mode_mix<<<dim3(BB / 2, CC / 2), 256, 0, stream>>>(Xf, sw_r, sw_i, omh, oml, l);
        inv_mfma<<<dim3(SS / 128, BB / 2), 256, 0, stream>>>(
            omh, oml, t2h, t2l, pw_w, pw_b, xh, xl, l, (l < 3) ? 1 : 0);
    }
    head_kernel<<<dim3(SS / 64, BB), 256, 0, stream>>>(xh, xl, fc1_w, fc1_b, fc2_w,
                                                       fc2_b, out);
}